// Round 3
// baseline (11352.083 us; speedup 1.0000x reference)
//
#include <hip/hip_runtime.h>
#include <math.h>

#define BATCH 16
#define NPTS  2048
#define DIM   768
#define KC    16

typedef double d4 __attribute__((ext_vector_type(4)));
typedef unsigned long long ull;

// ---------------- normalize: fn = f / max(||f||,1e-12), fp64 norm ----------------
__global__ void normalize_k(const float* __restrict__ feat, float* __restrict__ fn, int cs) {
  const int rn = blockIdx.x;                 // ci*NPTS + n
  const int ci = rn >> 11, n = rn & (NPTS - 1);
  const float* src = feat + ((size_t)(cs + ci) * NPTS + n) * DIM;
  const int t = threadIdx.x;                 // 256 threads
  float f0 = src[t], f1 = src[t + 256], f2 = src[t + 512];
  double s = (double)f0 * (double)f0 + (double)f1 * (double)f1 + (double)f2 * (double)f2;
  for (int off = 32; off > 0; off >>= 1) s += __shfl_down(s, off);
  __shared__ double ps[4];
  __shared__ double rbc;
  const int lane = t & 63, wid = t >> 6;
  if (lane == 0) ps[wid] = s;
  __syncthreads();
  if (t == 0) {
    double tot = ps[0] + ps[1] + ps[2] + ps[3];
    rbc = fmax(sqrt(tot), 1e-12);
  }
  __syncthreads();
  const double r = rbc;
  float* dst = fn + ((size_t)ci * NPTS + n) * DIM;
  dst[t]       = (float)((double)f0 / r);
  dst[t + 256] = (float)((double)f1 / r);
  dst[t + 512] = (float)((double)f2 / r);
}

// ---------------- similarity: S = fn.fn^T (fp64 MFMA) + 0.5*exp(-d2/1e4) ----------------
// Upper-triangle 128x128 tiles (bx<=by); mirror_k fills the rest.
// LDS holds fp32 tiles (fn is fp32; fp32->fp64 cvt at fragment read is EXACT, so the
// result is bit-identical to fp64 staging) -> 20 KB/block -> 3-4 blocks/CU resident.
__global__ __launch_bounds__(256, 4) void gemm_k(const float* __restrict__ fn,
                                                 const float* __restrict__ coords,
                                                 float* __restrict__ S, int cs) {
  if (blockIdx.x > blockIdx.y) return;       // symmetry: skip strictly-lower tiles
  const int ci = blockIdx.z;
  const int i0 = blockIdx.x * 128;
  const int j0 = blockIdx.y * 128;
  const int tid  = threadIdx.x;              // 256
  const int lane = tid & 63, w = tid >> 6;
  const int wr = (w >> 1) * 64, wc = (w & 1) * 64;   // wave quadrant
  const int lo = lane & 15, quad = lane >> 4;

  // [row][k] fp32, padded to 20 for 16B-aligned float4 stores (row*80 % 16 == 0)
  // and 2-lanes-per-bank (free) fragment reads.
  __shared__ float Af[128][20];
  __shared__ float Bf[128][20];

  d4 acc[4][4];
#pragma unroll
  for (int tr = 0; tr < 4; ++tr)
#pragma unroll
    for (int tc = 0; tc < 4; ++tc) acc[tr][tc] = (d4){0.0, 0.0, 0.0, 0.0};

  const float* fb = fn + (size_t)ci * NPTS * DIM;
  const int row  = tid >> 1;       // staging row 0..127
  const int half = tid & 1;
  const int kk0  = half * 8;
  const float* apBase = fb + (size_t)(i0 + row) * DIM + half * 8;
  const float* bpBase = fb + (size_t)(j0 + row) * DIM + half * 8;

  // prefetch chunk 0
  float4 pa0 = *(const float4*)(apBase);
  float4 pa1 = *(const float4*)(apBase + 4);
  float4 pb0 = *(const float4*)(bpBase);
  float4 pb1 = *(const float4*)(bpBase + 4);

  for (int k0 = 0; k0 < DIM; k0 += KC) {
    __syncthreads();   // previous chunk's readers done
    *(float4*)&Af[row][kk0]     = pa0;
    *(float4*)&Af[row][kk0 + 4] = pa1;
    *(float4*)&Bf[row][kk0]     = pb0;
    *(float4*)&Bf[row][kk0 + 4] = pb1;
    __syncthreads();
    if (k0 + KC < DIM) {           // prefetch next chunk; overlaps MFMA below
      pa0 = *(const float4*)(apBase + k0 + KC);
      pa1 = *(const float4*)(apBase + k0 + KC + 4);
      pb0 = *(const float4*)(bpBase + k0 + KC);
      pb1 = *(const float4*)(bpBase + k0 + KC + 4);
    }
#pragma unroll
    for (int k4 = 0; k4 < KC; k4 += 4) {
      const int kk = k4 + quad;    // this lane's k index
      double a0 = (double)Af[wr + lo +  0][kk];
      double a1 = (double)Af[wr + lo + 16][kk];
      double a2 = (double)Af[wr + lo + 32][kk];
      double a3 = (double)Af[wr + lo + 48][kk];
      double b0 = (double)Bf[wc + lo +  0][kk];
      double b1 = (double)Bf[wc + lo + 16][kk];
      double b2 = (double)Bf[wc + lo + 32][kk];
      double b3 = (double)Bf[wc + lo + 48][kk];
      acc[0][0] = __builtin_amdgcn_mfma_f64_16x16x4f64(a0, b0, acc[0][0], 0, 0, 0);
      acc[0][1] = __builtin_amdgcn_mfma_f64_16x16x4f64(a0, b1, acc[0][1], 0, 0, 0);
      acc[0][2] = __builtin_amdgcn_mfma_f64_16x16x4f64(a0, b2, acc[0][2], 0, 0, 0);
      acc[0][3] = __builtin_amdgcn_mfma_f64_16x16x4f64(a0, b3, acc[0][3], 0, 0, 0);
      acc[1][0] = __builtin_amdgcn_mfma_f64_16x16x4f64(a1, b0, acc[1][0], 0, 0, 0);
      acc[1][1] = __builtin_amdgcn_mfma_f64_16x16x4f64(a1, b1, acc[1][1], 0, 0, 0);
      acc[1][2] = __builtin_amdgcn_mfma_f64_16x16x4f64(a1, b2, acc[1][2], 0, 0, 0);
      acc[1][3] = __builtin_amdgcn_mfma_f64_16x16x4f64(a1, b3, acc[1][3], 0, 0, 0);
      acc[2][0] = __builtin_amdgcn_mfma_f64_16x16x4f64(a2, b0, acc[2][0], 0, 0, 0);
      acc[2][1] = __builtin_amdgcn_mfma_f64_16x16x4f64(a2, b1, acc[2][1], 0, 0, 0);
      acc[2][2] = __builtin_amdgcn_mfma_f64_16x16x4f64(a2, b2, acc[2][2], 0, 0, 0);
      acc[2][3] = __builtin_amdgcn_mfma_f64_16x16x4f64(a2, b3, acc[2][3], 0, 0, 0);
      acc[3][0] = __builtin_amdgcn_mfma_f64_16x16x4f64(a3, b0, acc[3][0], 0, 0, 0);
      acc[3][1] = __builtin_amdgcn_mfma_f64_16x16x4f64(a3, b1, acc[3][1], 0, 0, 0);
      acc[3][2] = __builtin_amdgcn_mfma_f64_16x16x4f64(a3, b2, acc[3][2], 0, 0, 0);
      acc[3][3] = __builtin_amdgcn_mfma_f64_16x16x4f64(a3, b3, acc[3][3], 0, 0, 0);
    }
  }

  // ---- probe the true C/D slot->(row,col) mapping ----
  d4 p1 = (d4){0.0, 0.0, 0.0, 0.0}, p2 = (d4){0.0, 0.0, 0.0, 0.0};
  p1 = __builtin_amdgcn_mfma_f64_16x16x4f64((double)lane, 1.0, p1, 0, 0, 0);
  p2 = __builtin_amdgcn_mfma_f64_16x16x4f64(1.0, (double)lane, p2, 0, 0, 0);
  int rowp[4], colp[4];
#pragma unroll
  for (int r = 0; r < 4; ++r) {
    rowp[r] = ((int)((p1[r] - 96.0) * 0.25)) & 15;
    colp[r] = ((int)((p2[r] - 96.0) * 0.25)) & 15;
  }

  // epilogue: + 0.5 * exp(-sq_dist/10000), exp via 4th-order Taylor (x<=2e-4, err ~1e-20)
  const float* cb = coords + (size_t)(cs + ci) * NPTS * 2;
  float* Sb = S + (size_t)ci * NPTS * NPTS;
#pragma unroll
  for (int r = 0; r < 4; ++r) {
    const int rl = rowp[r], cl = colp[r];
#pragma unroll
    for (int tr = 0; tr < 4; ++tr) {
      const int rowi = i0 + wr + tr * 16 + rl;
      float2 pi = *(const float2*)(cb + 2 * rowi);
      const double cix = pi.x, ciy = pi.y;
#pragma unroll
      for (int tc = 0; tc < 4; ++tc) {
        const int colj = j0 + wc + tc * 16 + cl;
        float2 pj = *(const float2*)(cb + 2 * colj);
        double dx = cix - (double)pj.x, dy = ciy - (double)pj.y;
        double x = (dx * dx + dy * dy) * (1.0 / 10000.0);
        double e = 1.0 - x * (1.0 - x * (0.5 - x * ((1.0 / 6.0) - x * (1.0 / 24.0))));
        Sb[(size_t)rowi * NPTS + colj] = (float)(acc[tr][tc][r] + 0.5 * e);
      }
    }
  }
}

// ---------------- mirror: fill strictly-lower 128-blocks from upper triangle ----------------
__global__ __launch_bounds__(256) void mirror_k(float* __restrict__ S) {
  const int Cb = blockIdx.x, Rb = blockIdx.y;
  if ((Rb >> 1) <= (Cb >> 1)) return;
  float* Sb = S + (size_t)blockIdx.z * NPTS * NPTS;
  __shared__ float t[64][65];
  const int lane = threadIdx.x & 63, w = threadIdx.x >> 6;
#pragma unroll
  for (int p = 0; p < 16; ++p) {
    const int r = w + 4 * p;
    t[r][lane] = Sb[(size_t)(Cb * 64 + r) * NPTS + Rb * 64 + lane];
  }
  __syncthreads();
#pragma unroll
  for (int p = 0; p < 16; ++p) {
    const int r = w + 4 * p;
    Sb[(size_t)(Rb * 64 + r) * NPTS + Cb * 64 + lane] = t[lane][r];
  }
}

// ---------------- monotone fp32 key: a > b (float) <=> mono(a) > mono(b) (uint) ----------------
__device__ __forceinline__ unsigned mono(float f) {
  unsigned u = __float_as_uint(f);
  return (u & 0x80000000u) ? ~u : (u | 0x80000000u);
}

// ---------------- packed u64 wave argmax: max key, tie -> min index ----------------
// value packed as (key<<32) | (2047 - idx); 64-bit max over the wave via DPP on halves.
#define DPP64_STEP(X, CTRL, RMASK) do {                                                   \
  unsigned lo_ = (unsigned)(X), hi_ = (unsigned)((X) >> 32);                              \
  unsigned lo2_ = (unsigned)__builtin_amdgcn_update_dpp((int)lo_, (int)lo_, CTRL, RMASK, 0xf, false); \
  unsigned hi2_ = (unsigned)__builtin_amdgcn_update_dpp((int)hi_, (int)hi_, CTRL, RMASK, 0xf, false); \
  ull o_ = ((ull)hi2_ << 32) | lo2_;                                                      \
  if (o_ > (X)) (X) = o_;                                                                 \
} while (0)

__device__ __forceinline__ ull wave_amax64(ull x) {
  DPP64_STEP(x, 0x111, 0xf);   // row_shr:1
  DPP64_STEP(x, 0x112, 0xf);   // row_shr:2
  DPP64_STEP(x, 0x114, 0xf);   // row_shr:4
  DPP64_STEP(x, 0x118, 0xf);   // row_shr:8
  DPP64_STEP(x, 0x142, 0xa);   // row_bcast:15 -> rows 1,3
  DPP64_STEP(x, 0x143, 0xc);   // row_bcast:31 -> rows 2,3
  unsigned lo = (unsigned)__builtin_amdgcn_readlane((int)(unsigned)x, 63);
  unsigned hi = (unsigned)__builtin_amdgcn_readlane((int)(unsigned)(x >> 32), 63);
  return ((ull)hi << 32) | lo;
}

// ---------------- cand_k: exact top-7 + tau(=8th max) per row (diag excluded) + fp64 rowsum ----
// Output: cand8[row*8 + e] for e<7: (mono(val)<<32)|(2047-idx). Slot 7: (mono(8th max)<<32).
__global__ __launch_bounds__(64) void cand_k(const float* __restrict__ S,
                                             ull* __restrict__ cand8,
                                             double* __restrict__ rs) {
  const size_t r = blockIdx.x;               // ci*NPTS + row
  const int row = (int)(r & (NPTS - 1));
  const float* rowp = S + r * NPTS;
  const int lane = threadIdx.x;

  float4 q[8];
  double sum = 0.0;
#pragma unroll
  for (int c = 0; c < 8; ++c) {
    q[c] = ((const float4*)rowp)[c * 64 + lane];
    sum += (double)q[c].x; sum += (double)q[c].y; sum += (double)q[c].z; sum += (double)q[c].w;
  }
  {
    double s2 = sum;
    for (int off = 32; off > 0; off >>= 1) s2 += __shfl_down(s2, off);
    if (lane == 0) rs[r] = s2;
  }

  // removal mask over this lane's 32 positions (bit 4c+s); pre-remove the diagonal.
  unsigned rem = 0;
  const int dd = row - 4 * lane;             // == c*256 + s if this lane owns the diag
  if (dd >= 0 && dd < 2048 && (dd & 0xFC) == 0) rem = 1u << (((dd >> 8) << 2) | (dd & 3));

  float bv; int bp;
  auto rescan = [&]() {
    bv = -INFINITY; bp = 0;
#pragma unroll
    for (int c = 0; c < 8; ++c) {
      const float xs0 = q[c].x, xs1 = q[c].y, xs2 = q[c].z, xs3 = q[c].w;
      float x0 = ((rem >> (4 * c + 0)) & 1u) ? -INFINITY : xs0;
      float x1 = ((rem >> (4 * c + 1)) & 1u) ? -INFINITY : xs1;
      float x2 = ((rem >> (4 * c + 2)) & 1u) ? -INFINITY : xs2;
      float x3 = ((rem >> (4 * c + 3)) & 1u) ? -INFINITY : xs3;
      if (x0 > bv) { bv = x0; bp = 4 * c + 0; }
      if (x1 > bv) { bv = x1; bp = 4 * c + 1; }
      if (x2 > bv) { bv = x2; bp = 4 * c + 2; }
      if (x3 > bv) { bv = x3; bp = 4 * c + 3; }
    }
  };
  rescan();

#pragma unroll 1
  for (int rnd = 0; rnd < 8; ++rnd) {
    const int gi = ((bp >> 2) << 8) + 4 * lane + (bp & 3);   // global column index
    const ull pk = ((ull)mono(bv) << 32) | (unsigned)(2047 - gi);
    const ull red = wave_amax64(pk);
    if (rnd < 7) {
      if (lane == 0) cand8[r * 8 + rnd] = red;
      if (pk == red) { rem |= 1u << bp; rescan(); }          // winner lane removes + rescans
    } else {
      if (lane == 0) cand8[r * 8 + 7] = (red >> 32) << 32;   // tau = 8th max, idx field 0
    }
  }
}

// ---------------- greedy traversal: LDS-resident compact candidate table ----------------
// 128 KiB dynamic LDS: 2048 rows x 8 x u64 (slots 0..6 candidates, slot 7 tau).
// Fast path: one broadcast ds_read_b64 + packed DPP argmax (~no global latency).
// Slow path: full S-row rescan; row loads are issued speculatively at step top into
// double-buffered registers so the L3/HBM latency hides under the fast-path logic.
__global__ __launch_bounds__(64) void traverse_k(const float* __restrict__ S,
                                                 const ull* __restrict__ cand8,
                                                 const double* __restrict__ rs,
                                                 float* __restrict__ order_f, int cs) {
  extern __shared__ ull tabL[];              // [NPTS*8]
  const int ci = blockIdx.x;
  const int gb = cs + ci;
  const int lane = threadIdx.x;

  // stage candidate table: 128KB, 8 loads in flight per burst
  {
    float4* ls = (float4*)tabL;
    const float4* gs = (const float4*)(cand8 + (size_t)ci * NPTS * 8);
#pragma unroll 1
    for (int i0 = 0; i0 < 8192; i0 += 512) {
      float4 t[8];
#pragma unroll
      for (int j = 0; j < 8; ++j) t[j] = gs[i0 + j * 64 + lane];
#pragma unroll
      for (int j = 0; j < 8; ++j) ls[i0 + j * 64 + lane] = t[j];
    }
  }
  __syncthreads();

  // start node: argmax of fp64 rowsum (tie -> min index)
  const double* rb = rs + (size_t)ci * NPTS;
  double dv = -1.0e300; int di = 0;
#pragma unroll
  for (int c = 0; c < 32; ++c) {
    int j = c * 64 + lane;
    double v = rb[j];
    if (v > dv) { dv = v; di = j; }
  }
  for (int off = 32; off > 0; off >>= 1) {
    double vo = __shfl_down(dv, off);
    int io = __shfl_down(di, off);
    if (vo > dv || (vo == dv && io < di)) { dv = vo; di = io; }
  }
  int cur = __shfl(di, 0);

  unsigned vis = 0, visw = 0;
  if (lane == ((cur >> 2) & 63)) vis |= 1u << (((cur >> 8) << 2) | (cur & 3));
  if (lane == (cur >> 5))        visw |= 1u << (cur & 31);
  if (lane == 0) order_f[(size_t)gb * NPTS] = (float)cur;

  const float* Sb = S + (size_t)ci * NPTS * NPTS;

  auto step = [&](int s, float4 (&v)[8]) {
    // speculative prefetch of row cur (consumed only on slow path)
    const float4* rowp = (const float4*)(Sb + (size_t)cur * NPTS);
#pragma unroll
    for (int c = 0; c < 8; ++c) v[c] = rowp[c * 64 + lane];
    __builtin_amdgcn_sched_barrier(0);       // pin issue point: loads first, then LDS path

    const ull e = tabL[cur * 8 + (lane & 7)];                 // broadcast ds_read_b64
    const unsigned tauv = (unsigned)__shfl((int)(unsigned)(e >> 32), 7);
    const unsigned idx = 2047u - (unsigned)(e & 0xFFFFFFFFu);
    const unsigned wv = (unsigned)__shfl((int)visw, (int)(idx >> 5));
    const ull masked = (((lane & 7) == 7) || ((wv >> (idx & 31)) & 1u)) ? 0ull : e;
    const ull m = wave_amax64(masked);
    int nxt;
    if ((unsigned)(m >> 32) > tauv) {
      nxt = (int)(2047u - (unsigned)(m & 0xFFFFFFFFu));
    } else {
      // slow path: full masked row scan (v[] already in flight)
      float bvv = -INFINITY; int bi = 0;
#pragma unroll
      for (int c = 0; c < 8; ++c) {
        const int base = c * 256 + 4 * lane;
        float x0 = (vis & (1u << (4 * c + 0))) ? -INFINITY : v[c].x;
        float x1 = (vis & (1u << (4 * c + 1))) ? -INFINITY : v[c].y;
        float x2 = (vis & (1u << (4 * c + 2))) ? -INFINITY : v[c].z;
        float x3 = (vis & (1u << (4 * c + 3))) ? -INFINITY : v[c].w;
        if (x0 > bvv) { bvv = x0; bi = base + 0; }
        if (x1 > bvv) { bvv = x1; bi = base + 1; }
        if (x2 > bvv) { bvv = x2; bi = base + 2; }
        if (x3 > bvv) { bvv = x3; bi = base + 3; }
      }
      const ull pk = ((ull)mono(bvv) << 32) | (unsigned)(2047 - bi);
      const ull mm = wave_amax64(pk);
      nxt = (int)(2047u - (unsigned)(mm & 0xFFFFFFFFu));
    }
    if (lane == ((nxt >> 2) & 63)) vis |= 1u << (((nxt >> 8) << 2) | (nxt & 3));
    if (lane == (nxt >> 5))        visw |= 1u << (nxt & 31);
    if (lane == 0) order_f[(size_t)gb * NPTS + s] = (float)nxt;
    cur = nxt;
  };

  float4 va[8], vb[8];
  int s = 1;
  for (; s + 1 < NPTS; s += 2) {             // 1023 pairs
    step(s, va);
    step(s + 1, vb);
  }
  step(s, va);                               // final odd step (s = 2047)
}

// ---------------- gather: reordered = features[order] ----------------
__global__ void gather_k(const float* __restrict__ feat, const float* __restrict__ order_f,
                         float* __restrict__ out) {
  const int bk = blockIdx.x;
  const int b = bk >> 11, k = bk & (NPTS - 1);
  const int idx = (int)order_f[(size_t)b * NPTS + k];
  const float4* src = (const float4*)(feat + ((size_t)b * NPTS + idx) * DIM);
  float4* dst = (float4*)(out + ((size_t)b * NPTS + k) * DIM);
  dst[threadIdx.x] = src[threadIdx.x];
}

extern "C" void kernel_launch(void* const* d_in, const int* in_sizes, int n_in,
                              void* d_out, int out_size, void* d_ws, size_t ws_size,
                              hipStream_t stream) {
  const float* features = (const float*)d_in[0];
  const float* coords   = (const float*)d_in[1];
  float* out = (float*)d_out;
  float* order_f = out + (size_t)BATCH * NPTS * DIM;

  // one-time: allow 128 KiB dynamic LDS on traverse_k (some ROCm builds cap at 64 KiB
  // without this attribute; host-side non-stream call, safe under graph capture)
  static bool attr_done = false;
  if (!attr_done) {
    hipFuncSetAttribute((const void*)traverse_k,
                        hipFuncAttributeMaxDynamicSharedMemorySize, 131072);
    attr_done = true;
  }

  // ws per batch: rs (N*8) + S (N*N*4) + fn (N*D*4) + cand8 (N*8*8)
  const size_t per_b = (size_t)NPTS * 8 + (size_t)NPTS * NPTS * 4 +
                       (size_t)NPTS * DIM * 4 + (size_t)NPTS * 8 * 8;
  int C = BATCH;
  while (C > 1 && per_b * (size_t)C > ws_size) C >>= 1;

  char* wp = (char*)d_ws;
  double* rowsum = (double*)wp;               wp += (size_t)C * NPTS * 8;
  float*  S      = (float*)wp;                wp += (size_t)C * NPTS * NPTS * 4;
  float*  fn     = (float*)wp;                wp += (size_t)C * NPTS * DIM * 4;
  ull*    cand8  = (ull*)wp;

  for (int cs = 0; cs < BATCH; cs += C) {
    normalize_k<<<dim3(C * NPTS), dim3(256), 0, stream>>>(features, fn, cs);
    gemm_k<<<dim3(16, 16, C), dim3(256), 0, stream>>>(fn, coords, S, cs);
    mirror_k<<<dim3(32, 32, C), dim3(256), 0, stream>>>(S);
    cand_k<<<dim3(C * NPTS), dim3(64), 0, stream>>>(S, cand8, rowsum);
    traverse_k<<<dim3(C), dim3(64), 131072, stream>>>(S, cand8, rowsum, order_f, cs);
  }
  gather_k<<<dim3(BATCH * NPTS), dim3(192), 0, stream>>>(features, order_f, out);
}

// Round 4
// 2618.675 us; speedup vs baseline: 4.3350x; 4.3350x over previous
//
#include <hip/hip_runtime.h>
#include <math.h>

#define BATCH 16
#define NPTS  2048
#define DIM   768
#define KC    16

typedef double d4 __attribute__((ext_vector_type(4)));
typedef unsigned long long ull;

// ---------------- normalize: fn = f / max(||f||,1e-12), fp64 norm ----------------
__global__ void normalize_k(const float* __restrict__ feat, float* __restrict__ fn, int cs) {
  const int rn = blockIdx.x;                 // ci*NPTS + n
  const int ci = rn >> 11, n = rn & (NPTS - 1);
  const float* src = feat + ((size_t)(cs + ci) * NPTS + n) * DIM;
  const int t = threadIdx.x;                 // 256 threads
  float f0 = src[t], f1 = src[t + 256], f2 = src[t + 512];
  double s = (double)f0 * (double)f0 + (double)f1 * (double)f1 + (double)f2 * (double)f2;
  for (int off = 32; off > 0; off >>= 1) s += __shfl_down(s, off);
  __shared__ double ps[4];
  __shared__ double rbc;
  const int lane = t & 63, wid = t >> 6;
  if (lane == 0) ps[wid] = s;
  __syncthreads();
  if (t == 0) {
    double tot = ps[0] + ps[1] + ps[2] + ps[3];
    rbc = fmax(sqrt(tot), 1e-12);
  }
  __syncthreads();
  const double r = rbc;
  float* dst = fn + ((size_t)ci * NPTS + n) * DIM;
  dst[t]       = (float)((double)f0 / r);
  dst[t + 256] = (float)((double)f1 / r);
  dst[t + 512] = (float)((double)f2 / r);
}

// ---------------- similarity: S = fn.fn^T (fp64 MFMA) + 0.5*exp(-d2/1e4) ----------------
// Upper-triangle 128x128 tiles (bx<=by); mirror_k fills the rest.
// LDS tiles are fp32 in [k][row] layout, row-stride 144 (144 mod 32 == 16):
//   - staging writes: 64 lanes -> 2 lanes/bank (free, m136)
//   - fragment reads: quads pair onto 16-bank halves -> 2 lanes/bank (free)
// fp32->fp64 cvt at read is EXACT and accumulation order is unchanged, so S is
// bit-identical to the fp64-staged round-2 kernel. 18.4 KB LDS/block -> 2 blocks/CU.
// launch_bounds stays (256,2): the 128-VGPR fp64 accumulator must not be capped
// (256,4 forced a 30 GB/dispatch scratch spill in round 3).
__global__ __launch_bounds__(256, 2) void gemm_k(const float* __restrict__ fn,
                                                 const float* __restrict__ coords,
                                                 float* __restrict__ S, int cs) {
  if (blockIdx.x > blockIdx.y) return;       // symmetry: skip strictly-lower tiles
  const int ci = blockIdx.z;
  const int i0 = blockIdx.x * 128;
  const int j0 = blockIdx.y * 128;
  const int tid  = threadIdx.x;              // 256
  const int lane = tid & 63, w = tid >> 6;
  const int wr = (w >> 1) * 64, wc = (w & 1) * 64;   // wave quadrant
  const int lo = lane & 15, quad = lane >> 4;

  __shared__ float Af[KC][144];   // [k][i], fp32
  __shared__ float Bf[KC][144];   // [k][j], fp32

  d4 acc[4][4];
#pragma unroll
  for (int tr = 0; tr < 4; ++tr)
#pragma unroll
    for (int tc = 0; tc < 4; ++tc) acc[tr][tc] = (d4){0.0, 0.0, 0.0, 0.0};

  const float* fb = fn + (size_t)ci * NPTS * DIM;
  const int row  = tid >> 1;       // staging row 0..127
  const int half = tid & 1;
  const int kk0  = half * 8;
  const float* apBase = fb + (size_t)(i0 + row) * DIM + half * 8;
  const float* bpBase = fb + (size_t)(j0 + row) * DIM + half * 8;

  // prefetch chunk 0
  float4 pa0 = *(const float4*)(apBase);
  float4 pa1 = *(const float4*)(apBase + 4);
  float4 pb0 = *(const float4*)(bpBase);
  float4 pb1 = *(const float4*)(bpBase + 4);

  for (int k0 = 0; k0 < DIM; k0 += KC) {
    __syncthreads();   // previous chunk's readers done
    Af[kk0 + 0][row] = pa0.x; Af[kk0 + 1][row] = pa0.y; Af[kk0 + 2][row] = pa0.z; Af[kk0 + 3][row] = pa0.w;
    Af[kk0 + 4][row] = pa1.x; Af[kk0 + 5][row] = pa1.y; Af[kk0 + 6][row] = pa1.z; Af[kk0 + 7][row] = pa1.w;
    Bf[kk0 + 0][row] = pb0.x; Bf[kk0 + 1][row] = pb0.y; Bf[kk0 + 2][row] = pb0.z; Bf[kk0 + 3][row] = pb0.w;
    Bf[kk0 + 4][row] = pb1.x; Bf[kk0 + 5][row] = pb1.y; Bf[kk0 + 6][row] = pb1.z; Bf[kk0 + 7][row] = pb1.w;
    __syncthreads();
    if (k0 + KC < DIM) {           // prefetch next chunk; overlaps MFMA below
      pa0 = *(const float4*)(apBase + k0 + KC);
      pa1 = *(const float4*)(apBase + k0 + KC + 4);
      pb0 = *(const float4*)(bpBase + k0 + KC);
      pb1 = *(const float4*)(bpBase + k0 + KC + 4);
    }
#pragma unroll
    for (int k4 = 0; k4 < KC; k4 += 4) {
      const int kk = k4 + quad;    // this lane's k index
      double a0 = (double)Af[kk][wr + lo +  0];
      double a1 = (double)Af[kk][wr + lo + 16];
      double a2 = (double)Af[kk][wr + lo + 32];
      double a3 = (double)Af[kk][wr + lo + 48];
      double b0 = (double)Bf[kk][wc + lo +  0];
      double b1 = (double)Bf[kk][wc + lo + 16];
      double b2 = (double)Bf[kk][wc + lo + 32];
      double b3 = (double)Bf[kk][wc + lo + 48];
      acc[0][0] = __builtin_amdgcn_mfma_f64_16x16x4f64(a0, b0, acc[0][0], 0, 0, 0);
      acc[0][1] = __builtin_amdgcn_mfma_f64_16x16x4f64(a0, b1, acc[0][1], 0, 0, 0);
      acc[0][2] = __builtin_amdgcn_mfma_f64_16x16x4f64(a0, b2, acc[0][2], 0, 0, 0);
      acc[0][3] = __builtin_amdgcn_mfma_f64_16x16x4f64(a0, b3, acc[0][3], 0, 0, 0);
      acc[1][0] = __builtin_amdgcn_mfma_f64_16x16x4f64(a1, b0, acc[1][0], 0, 0, 0);
      acc[1][1] = __builtin_amdgcn_mfma_f64_16x16x4f64(a1, b1, acc[1][1], 0, 0, 0);
      acc[1][2] = __builtin_amdgcn_mfma_f64_16x16x4f64(a1, b2, acc[1][2], 0, 0, 0);
      acc[1][3] = __builtin_amdgcn_mfma_f64_16x16x4f64(a1, b3, acc[1][3], 0, 0, 0);
      acc[2][0] = __builtin_amdgcn_mfma_f64_16x16x4f64(a2, b0, acc[2][0], 0, 0, 0);
      acc[2][1] = __builtin_amdgcn_mfma_f64_16x16x4f64(a2, b1, acc[2][1], 0, 0, 0);
      acc[2][2] = __builtin_amdgcn_mfma_f64_16x16x4f64(a2, b2, acc[2][2], 0, 0, 0);
      acc[2][3] = __builtin_amdgcn_mfma_f64_16x16x4f64(a2, b3, acc[2][3], 0, 0, 0);
      acc[3][0] = __builtin_amdgcn_mfma_f64_16x16x4f64(a3, b0, acc[3][0], 0, 0, 0);
      acc[3][1] = __builtin_amdgcn_mfma_f64_16x16x4f64(a3, b1, acc[3][1], 0, 0, 0);
      acc[3][2] = __builtin_amdgcn_mfma_f64_16x16x4f64(a3, b2, acc[3][2], 0, 0, 0);
      acc[3][3] = __builtin_amdgcn_mfma_f64_16x16x4f64(a3, b3, acc[3][3], 0, 0, 0);
    }
  }

  // ---- probe the true C/D slot->(row,col) mapping ----
  d4 p1 = (d4){0.0, 0.0, 0.0, 0.0}, p2 = (d4){0.0, 0.0, 0.0, 0.0};
  p1 = __builtin_amdgcn_mfma_f64_16x16x4f64((double)lane, 1.0, p1, 0, 0, 0);
  p2 = __builtin_amdgcn_mfma_f64_16x16x4f64(1.0, (double)lane, p2, 0, 0, 0);
  int rowp[4], colp[4];
#pragma unroll
  for (int r = 0; r < 4; ++r) {
    rowp[r] = ((int)((p1[r] - 96.0) * 0.25)) & 15;
    colp[r] = ((int)((p2[r] - 96.0) * 0.25)) & 15;
  }

  // epilogue: + 0.5 * exp(-sq_dist/10000), exp via 4th-order Taylor (x<=2e-4, err ~1e-20)
  const float* cb = coords + (size_t)(cs + ci) * NPTS * 2;
  float* Sb = S + (size_t)ci * NPTS * NPTS;
#pragma unroll
  for (int r = 0; r < 4; ++r) {
    const int rl = rowp[r], cl = colp[r];
#pragma unroll
    for (int tr = 0; tr < 4; ++tr) {
      const int rowi = i0 + wr + tr * 16 + rl;
      float2 pi = *(const float2*)(cb + 2 * rowi);
      const double cix = pi.x, ciy = pi.y;
#pragma unroll
      for (int tc = 0; tc < 4; ++tc) {
        const int colj = j0 + wc + tc * 16 + cl;
        float2 pj = *(const float2*)(cb + 2 * colj);
        double dx = cix - (double)pj.x, dy = ciy - (double)pj.y;
        double x = (dx * dx + dy * dy) * (1.0 / 10000.0);
        double e = 1.0 - x * (1.0 - x * (0.5 - x * ((1.0 / 6.0) - x * (1.0 / 24.0))));
        Sb[(size_t)rowi * NPTS + colj] = (float)(acc[tr][tc][r] + 0.5 * e);
      }
    }
  }
}

// ---------------- mirror: fill strictly-lower 128-blocks from upper triangle ----------------
__global__ __launch_bounds__(256) void mirror_k(float* __restrict__ S) {
  const int Cb = blockIdx.x, Rb = blockIdx.y;
  if ((Rb >> 1) <= (Cb >> 1)) return;
  float* Sb = S + (size_t)blockIdx.z * NPTS * NPTS;
  __shared__ float t[64][65];
  const int lane = threadIdx.x & 63, w = threadIdx.x >> 6;
#pragma unroll
  for (int p = 0; p < 16; ++p) {
    const int r = w + 4 * p;
    t[r][lane] = Sb[(size_t)(Cb * 64 + r) * NPTS + Rb * 64 + lane];
  }
  __syncthreads();
#pragma unroll
  for (int p = 0; p < 16; ++p) {
    const int r = w + 4 * p;
    Sb[(size_t)(Rb * 64 + r) * NPTS + Cb * 64 + lane] = t[lane][r];
  }
}

// ---------------- monotone fp32 key: a > b (float) <=> mono(a) > mono(b) (uint) ----------------
__device__ __forceinline__ unsigned mono(float f) {
  unsigned u = __float_as_uint(f);
  return (u & 0x80000000u) ? ~u : (u | 0x80000000u);
}

// ---------------- packed u64 wave argmax: max key, tie -> min index ----------------
// value packed as (key<<32) | (2047 - idx); 64-bit max over the wave via DPP on halves.
#define DPP64_STEP(X, CTRL, RMASK) do {                                                   \
  unsigned lo_ = (unsigned)(X), hi_ = (unsigned)((X) >> 32);                              \
  unsigned lo2_ = (unsigned)__builtin_amdgcn_update_dpp((int)lo_, (int)lo_, CTRL, RMASK, 0xf, false); \
  unsigned hi2_ = (unsigned)__builtin_amdgcn_update_dpp((int)hi_, (int)hi_, CTRL, RMASK, 0xf, false); \
  ull o_ = ((ull)hi2_ << 32) | lo2_;                                                      \
  if (o_ > (X)) (X) = o_;                                                                 \
} while (0)

__device__ __forceinline__ ull wave_amax64(ull x) {
  DPP64_STEP(x, 0x111, 0xf);   // row_shr:1
  DPP64_STEP(x, 0x112, 0xf);   // row_shr:2
  DPP64_STEP(x, 0x114, 0xf);   // row_shr:4
  DPP64_STEP(x, 0x118, 0xf);   // row_shr:8
  DPP64_STEP(x, 0x142, 0xa);   // row_bcast:15 -> rows 1,3
  DPP64_STEP(x, 0x143, 0xc);   // row_bcast:31 -> rows 2,3
  unsigned lo = (unsigned)__builtin_amdgcn_readlane((int)(unsigned)x, 63);
  unsigned hi = (unsigned)__builtin_amdgcn_readlane((int)(unsigned)(x >> 32), 63);
  return ((ull)hi << 32) | lo;
}

// ---------------- cand_k: exact top-7 + tau(=8th max) per row (diag excluded) + fp64 rowsum ----
// Output: cand8[row*8 + e] for e<7: (mono(val)<<32)|(2047-idx). Slot 7: (mono(8th max)<<32).
__global__ __launch_bounds__(64) void cand_k(const float* __restrict__ S,
                                             ull* __restrict__ cand8,
                                             double* __restrict__ rs) {
  const size_t r = blockIdx.x;               // ci*NPTS + row
  const int row = (int)(r & (NPTS - 1));
  const float* rowp = S + r * NPTS;
  const int lane = threadIdx.x;

  float4 q[8];
  double sum = 0.0;
#pragma unroll
  for (int c = 0; c < 8; ++c) {
    q[c] = ((const float4*)rowp)[c * 64 + lane];
    sum += (double)q[c].x; sum += (double)q[c].y; sum += (double)q[c].z; sum += (double)q[c].w;
  }
  {
    double s2 = sum;
    for (int off = 32; off > 0; off >>= 1) s2 += __shfl_down(s2, off);
    if (lane == 0) rs[r] = s2;
  }

  // removal mask over this lane's 32 positions (bit 4c+s); pre-remove the diagonal.
  unsigned rem = 0;
  const int dd = row - 4 * lane;             // == c*256 + s if this lane owns the diag
  if (dd >= 0 && dd < 2048 && (dd & 0xFC) == 0) rem = 1u << (((dd >> 8) << 2) | (dd & 3));

  float bv; int bp;
  auto rescan = [&]() {
    bv = -INFINITY; bp = 0;
#pragma unroll
    for (int c = 0; c < 8; ++c) {
      const float xs0 = q[c].x, xs1 = q[c].y, xs2 = q[c].z, xs3 = q[c].w;
      float x0 = ((rem >> (4 * c + 0)) & 1u) ? -INFINITY : xs0;
      float x1 = ((rem >> (4 * c + 1)) & 1u) ? -INFINITY : xs1;
      float x2 = ((rem >> (4 * c + 2)) & 1u) ? -INFINITY : xs2;
      float x3 = ((rem >> (4 * c + 3)) & 1u) ? -INFINITY : xs3;
      if (x0 > bv) { bv = x0; bp = 4 * c + 0; }
      if (x1 > bv) { bv = x1; bp = 4 * c + 1; }
      if (x2 > bv) { bv = x2; bp = 4 * c + 2; }
      if (x3 > bv) { bv = x3; bp = 4 * c + 3; }
    }
  };
  rescan();

#pragma unroll 1
  for (int rnd = 0; rnd < 8; ++rnd) {
    const int gi = ((bp >> 2) << 8) + 4 * lane + (bp & 3);   // global column index
    const ull pk = ((ull)mono(bv) << 32) | (unsigned)(2047 - gi);
    const ull red = wave_amax64(pk);
    if (rnd < 7) {
      if (lane == 0) cand8[r * 8 + rnd] = red;
      if (pk == red) { rem |= 1u << bp; rescan(); }          // winner lane removes + rescans
    } else {
      if (lane == 0) cand8[r * 8 + 7] = (red >> 32) << 32;   // tau = 8th max, idx field 0
    }
  }
}

// ---------------- greedy traversal: LDS-resident compact candidate table ----------------
// 128 KiB dynamic LDS: 2048 rows x 8 x u64 (slots 0..6 candidates, slot 7 tau).
// Fast path: one broadcast ds_read_b64 + packed DPP argmax (~no global latency).
// Slow path: full S-row rescan; row loads are issued speculatively at step top into
// double-buffered registers so the L3/HBM latency hides under the fast-path logic.
__global__ __launch_bounds__(64) void traverse_k(const float* __restrict__ S,
                                                 const ull* __restrict__ cand8,
                                                 const double* __restrict__ rs,
                                                 float* __restrict__ order_f, int cs) {
  extern __shared__ ull tabL[];              // [NPTS*8]
  const int ci = blockIdx.x;
  const int gb = cs + ci;
  const int lane = threadIdx.x;

  // stage candidate table: 128KB, 8 loads in flight per burst
  {
    float4* ls = (float4*)tabL;
    const float4* gs = (const float4*)(cand8 + (size_t)ci * NPTS * 8);
#pragma unroll 1
    for (int i0 = 0; i0 < 8192; i0 += 512) {
      float4 t[8];
#pragma unroll
      for (int j = 0; j < 8; ++j) t[j] = gs[i0 + j * 64 + lane];
#pragma unroll
      for (int j = 0; j < 8; ++j) ls[i0 + j * 64 + lane] = t[j];
    }
  }
  __syncthreads();

  // start node: argmax of fp64 rowsum (tie -> min index)
  const double* rb = rs + (size_t)ci * NPTS;
  double dv = -1.0e300; int di = 0;
#pragma unroll
  for (int c = 0; c < 32; ++c) {
    int j = c * 64 + lane;
    double v = rb[j];
    if (v > dv) { dv = v; di = j; }
  }
  for (int off = 32; off > 0; off >>= 1) {
    double vo = __shfl_down(dv, off);
    int io = __shfl_down(di, off);
    if (vo > dv || (vo == dv && io < di)) { dv = vo; di = io; }
  }
  int cur = __shfl(di, 0);

  unsigned vis = 0, visw = 0;
  if (lane == ((cur >> 2) & 63)) vis |= 1u << (((cur >> 8) << 2) | (cur & 3));
  if (lane == (cur >> 5))        visw |= 1u << (cur & 31);
  if (lane == 0) order_f[(size_t)gb * NPTS] = (float)cur;

  const float* Sb = S + (size_t)ci * NPTS * NPTS;

  auto step = [&](int s, float4 (&v)[8]) {
    // speculative prefetch of row cur (consumed only on slow path)
    const float4* rowp = (const float4*)(Sb + (size_t)cur * NPTS);
#pragma unroll
    for (int c = 0; c < 8; ++c) v[c] = rowp[c * 64 + lane];
    __builtin_amdgcn_sched_barrier(0);       // pin issue point: loads first, then LDS path

    const ull e = tabL[cur * 8 + (lane & 7)];                 // broadcast ds_read_b64
    const unsigned tauv = (unsigned)__shfl((int)(unsigned)(e >> 32), 7);
    const unsigned idx = 2047u - (unsigned)(e & 0xFFFFFFFFu);
    const unsigned wv = (unsigned)__shfl((int)visw, (int)(idx >> 5));
    const ull masked = (((lane & 7) == 7) || ((wv >> (idx & 31)) & 1u)) ? 0ull : e;
    const ull m = wave_amax64(masked);
    int nxt;
    if ((unsigned)(m >> 32) > tauv) {
      nxt = (int)(2047u - (unsigned)(m & 0xFFFFFFFFu));
    } else {
      // slow path: full masked row scan (v[] already in flight)
      float bvv = -INFINITY; int bi = 0;
#pragma unroll
      for (int c = 0; c < 8; ++c) {
        const int base = c * 256 + 4 * lane;
        float x0 = (vis & (1u << (4 * c + 0))) ? -INFINITY : v[c].x;
        float x1 = (vis & (1u << (4 * c + 1))) ? -INFINITY : v[c].y;
        float x2 = (vis & (1u << (4 * c + 2))) ? -INFINITY : v[c].z;
        float x3 = (vis & (1u << (4 * c + 3))) ? -INFINITY : v[c].w;
        if (x0 > bvv) { bvv = x0; bi = base + 0; }
        if (x1 > bvv) { bvv = x1; bi = base + 1; }
        if (x2 > bvv) { bvv = x2; bi = base + 2; }
        if (x3 > bvv) { bvv = x3; bi = base + 3; }
      }
      const ull pk = ((ull)mono(bvv) << 32) | (unsigned)(2047 - bi);
      const ull mm = wave_amax64(pk);
      nxt = (int)(2047u - (unsigned)(mm & 0xFFFFFFFFu));
    }
    if (lane == ((nxt >> 2) & 63)) vis |= 1u << (((nxt >> 8) << 2) | (nxt & 3));
    if (lane == (nxt >> 5))        visw |= 1u << (nxt & 31);
    if (lane == 0) order_f[(size_t)gb * NPTS + s] = (float)nxt;
    cur = nxt;
  };

  float4 va[8], vb[8];
  int s = 1;
  for (; s + 1 < NPTS; s += 2) {             // 1023 pairs
    step(s, va);
    step(s + 1, vb);
  }
  step(s, va);                               // final odd step (s = 2047)
}

// ---------------- gather: reordered = features[order] ----------------
__global__ void gather_k(const float* __restrict__ feat, const float* __restrict__ order_f,
                         float* __restrict__ out) {
  const int bk = blockIdx.x;
  const int b = bk >> 11, k = bk & (NPTS - 1);
  const int idx = (int)order_f[(size_t)b * NPTS + k];
  const float4* src = (const float4*)(feat + ((size_t)b * NPTS + idx) * DIM);
  float4* dst = (float4*)(out + ((size_t)b * NPTS + k) * DIM);
  dst[threadIdx.x] = src[threadIdx.x];
}

extern "C" void kernel_launch(void* const* d_in, const int* in_sizes, int n_in,
                              void* d_out, int out_size, void* d_ws, size_t ws_size,
                              hipStream_t stream) {
  const float* features = (const float*)d_in[0];
  const float* coords   = (const float*)d_in[1];
  float* out = (float*)d_out;
  float* order_f = out + (size_t)BATCH * NPTS * DIM;

  // one-time: allow 128 KiB dynamic LDS on traverse_k (some ROCm builds cap at 64 KiB
  // without this attribute; host-side non-stream call, safe under graph capture)
  static bool attr_done = false;
  if (!attr_done) {
    hipFuncSetAttribute((const void*)traverse_k,
                        hipFuncAttributeMaxDynamicSharedMemorySize, 131072);
    attr_done = true;
  }

  // ws per batch: rs (N*8) + S (N*N*4) + fn (N*D*4) + cand8 (N*8*8)
  const size_t per_b = (size_t)NPTS * 8 + (size_t)NPTS * NPTS * 4 +
                       (size_t)NPTS * DIM * 4 + (size_t)NPTS * 8 * 8;
  int C = BATCH;
  while (C > 1 && per_b * (size_t)C > ws_size) C >>= 1;

  char* wp = (char*)d_ws;
  double* rowsum = (double*)wp;               wp += (size_t)C * NPTS * 8;
  float*  S      = (float*)wp;                wp += (size_t)C * NPTS * NPTS * 4;
  float*  fn     = (float*)wp;                wp += (size_t)C * NPTS * DIM * 4;
  ull*    cand8  = (ull*)wp;

  for (int cs = 0; cs < BATCH; cs += C) {
    normalize_k<<<dim3(C * NPTS), dim3(256), 0, stream>>>(features, fn, cs);
    gemm_k<<<dim3(16, 16, C), dim3(256), 0, stream>>>(fn, coords, S, cs);
    mirror_k<<<dim3(32, 32, C), dim3(256), 0, stream>>>(S);
    cand_k<<<dim3(C * NPTS), dim3(64), 0, stream>>>(S, cand8, rowsum);
    traverse_k<<<dim3(C), dim3(64), 131072, stream>>>(S, cand8, rowsum, order_f, cs);
  }
  gather_k<<<dim3(BATCH * NPTS), dim3(192), 0, stream>>>(features, order_f, out);
}